// Round 1
// baseline (2161.069 us; speedup 1.0000x reference)
//
#include <hip/hip_runtime.h>
#include <hip/hip_bf16.h>

#define N_NODES 32768
#define N_EDGES 524288
#define DD 128
#define B_GRAPHS 512

// ---------------- utility ----------------
__device__ __forceinline__ float gelu_exact(float z) {
    return 0.5f * z * (1.0f + erff(z * 0.70710678118654752440f));
}

// ---------------- CSR build ----------------
__global__ void k_zero(int* __restrict__ p, int n) {
    int i = blockIdx.x * blockDim.x + threadIdx.x;
    if (i < n) p[i] = 0;
}

__global__ void k_deg(const int* __restrict__ dst, int* __restrict__ deg) {
    int e = blockIdx.x * blockDim.x + threadIdx.x;
    if (e < N_EDGES) atomicAdd(&deg[dst[e]], 1);
}

__global__ __launch_bounds__(1024) void k_scan(const int* __restrict__ deg,
                                               int* __restrict__ offs,
                                               int* __restrict__ cursor) {
    int tid = threadIdx.x;
    int lane = tid & 63, wid = tid >> 6;
    int base = tid * 32;
    int pref[32];
    int run = 0;
    #pragma unroll
    for (int i = 0; i < 32; i++) { pref[i] = run; run += deg[base + i]; }
    int s = run;
    for (int m = 1; m < 64; m <<= 1) { int t = __shfl_up(s, m); if (lane >= m) s += t; }
    __shared__ int wsum[16];
    if (lane == 63) wsum[wid] = s;
    __syncthreads();
    if (tid < 16) {
        int v = wsum[tid];
        for (int m = 1; m < 16; m <<= 1) { int t = __shfl_up(v, m, 16); if (tid >= m) v += t; }
        wsum[tid] = v;
    }
    __syncthreads();
    int wbase = wid ? wsum[wid - 1] : 0;
    int ebase = wbase + (s - run);        // exclusive prefix for this thread
    #pragma unroll
    for (int i = 0; i < 32; i++) {
        int o = ebase + pref[i];
        offs[base + i] = o;
        cursor[base + i] = o;
    }
    if (tid == 1023) offs[N_NODES] = ebase + run;
}

__global__ void k_scatter(const int* __restrict__ src, const int* __restrict__ dst,
                          const int* __restrict__ attr, int* __restrict__ cursor,
                          int* __restrict__ csr) {
    int e = blockIdx.x * blockDim.x + threadIdx.x;
    if (e < N_EDGES) {
        int p = atomicAdd(&cursor[dst[e]], 1);
        csr[p] = src[e] | (attr[e] << 16);
    }
}

// ---------------- x init: masked gather + atom embedding ----------------
__global__ void k_build_x(const float* __restrict__ logits, const int* __restrict__ feat,
                          const float* __restrict__ aemb, float* __restrict__ x) {
    int idx = blockIdx.x * blockDim.x + threadIdx.x;   // float4 id, N_NODES*32 total
    int n = idx >> 5, c = idx & 31;
    int srow = ((n >> 6) << 7) + (n & 63);             // analytic nonzero(mask) index
    float4 lv = ((const float4*)logits)[srow * 32 + c];
    float4 av = ((const float4*)aemb)[feat[n] * 32 + c];
    float4 o;
    o.x = lv.x + av.x; o.y = lv.y + av.y; o.z = lv.z + av.z; o.w = lv.w + av.w;
    ((float4*)x)[idx] = o;
}

// ---------------- per-node aggregation (atomic-free via CSR) ----------------
__global__ __launch_bounds__(256) void k_agg(const float* __restrict__ x,
                                             const int* __restrict__ offs,
                                             const int* __restrict__ csr,
                                             const float* __restrict__ eemb,
                                             float* __restrict__ agg) {
    __shared__ float semb[8 * 128];
    int tid = threadIdx.x;
    for (int i = tid; i < 1024; i += 256) semb[i] = eemb[i];
    __syncthreads();
    int node = blockIdx.x * 4 + (tid >> 6);
    int lane = tid & 63;
    int o0 = offs[node], o1 = offs[node + 1];
    float2 acc = make_float2(0.f, 0.f);
    for (int e = o0; e < o1; e++) {
        int pk = csr[e];
        int s = pk & 0xFFFF, a = pk >> 16;
        float2 xv = *(const float2*)&x[s * 128 + lane * 2];
        float2 ev = *(const float2*)&semb[a * 128 + lane * 2];
        acc.x += fmaxf(xv.x + ev.x, 0.f);
        acc.y += fmaxf(xv.y + ev.y, 0.f);
    }
    *(float2*)&agg[node * 128 + lane * 2] = acc;
}

// ---------------- GEMM1: C[32768,256] = act(A[32768,128] @ W[128,256] + b) ----------------
// BM=64, BN=64, BK=64 (2 stages), 256 threads, 4x4 thread tile
__global__ __launch_bounds__(256) void k_gemm1(const float* __restrict__ A,
                                               const float* __restrict__ W,
                                               const float* __restrict__ bias,
                                               float* __restrict__ C, int relu) {
    __shared__ float As[64][68];
    __shared__ float Ws[64][68];
    int tid = threadIdx.x;
    int row0 = blockIdx.y * 64, n0 = blockIdx.x * 64;
    int tx = tid & 15, ty = tid >> 4;
    float acc[4][4] = {};
    for (int st = 0; st < 2; st++) {
        #pragma unroll
        for (int j = 0; j < 4; j++) {
            int lin = tid + j * 256;
            int k4 = lin & 15, m = lin >> 4;
            float4 v = ((const float4*)A)[(row0 + m) * 32 + st * 16 + k4];
            *(float4*)&As[m][k4 * 4] = v;
        }
        #pragma unroll
        for (int j = 0; j < 4; j++) {
            int lin = tid + j * 256;
            int n4 = lin & 15, k = lin >> 4;
            float4 v = ((const float4*)W)[(st * 64 + k) * 64 + (n0 >> 2) + n4];
            *(float4*)&Ws[k][n4 * 4] = v;
        }
        __syncthreads();
        #pragma unroll
        for (int k0 = 0; k0 < 64; k0 += 4) {
            float4 av[4];
            #pragma unroll
            for (int i = 0; i < 4; i++) av[i] = *(const float4*)&As[ty * 4 + i][k0];
            #pragma unroll
            for (int kk = 0; kk < 4; kk++) {
                float4 wv = *(const float4*)&Ws[k0 + kk][tx * 4];
                #pragma unroll
                for (int i = 0; i < 4; i++) {
                    float a = kk == 0 ? av[i].x : kk == 1 ? av[i].y : kk == 2 ? av[i].z : av[i].w;
                    acc[i][0] += a * wv.x; acc[i][1] += a * wv.y;
                    acc[i][2] += a * wv.z; acc[i][3] += a * wv.w;
                }
            }
        }
        __syncthreads();
    }
    float4 bv = ((const float4*)bias)[(n0 >> 2) + tx];
    #pragma unroll
    for (int i = 0; i < 4; i++) {
        float4 o;
        o.x = acc[i][0] + bv.x; o.y = acc[i][1] + bv.y;
        o.z = acc[i][2] + bv.z; o.w = acc[i][3] + bv.w;
        if (relu) {
            o.x = fmaxf(o.x, 0.f); o.y = fmaxf(o.y, 0.f);
            o.z = fmaxf(o.z, 0.f); o.w = fmaxf(o.w, 0.f);
        }
        ((float4*)C)[(row0 + ty * 4 + i) * 64 + (n0 >> 2) + tx] = o;
    }
}

// ---------------- GEMM2 + LN + residual: x += LN(T[32768,256] @ W[256,128] + b) ----------------
// BM=64, BN=128 (full), BK=64 (4 stages), 256 threads, 4x8 thread tile
__global__ __launch_bounds__(256) void k_gemm2(const float* __restrict__ T,
                                               const float* __restrict__ W,
                                               const float* __restrict__ bias,
                                               const float* __restrict__ lng,
                                               const float* __restrict__ lnb,
                                               float* __restrict__ x) {
    __shared__ float As[64][68];
    __shared__ float Ws[64][132];
    int tid = threadIdx.x;
    int row0 = blockIdx.x * 64;
    int tx = tid & 15, ty = tid >> 4;
    float acc[4][8] = {};
    for (int st = 0; st < 4; st++) {
        #pragma unroll
        for (int j = 0; j < 4; j++) {
            int lin = tid + j * 256;
            int k4 = lin & 15, m = lin >> 4;
            float4 v = ((const float4*)T)[(row0 + m) * 64 + st * 16 + k4];
            *(float4*)&As[m][k4 * 4] = v;
        }
        #pragma unroll
        for (int j = 0; j < 8; j++) {
            int lin = tid + j * 256;
            int n4 = lin & 31, k = lin >> 5;
            float4 v = ((const float4*)W)[(st * 64 + k) * 32 + n4];
            *(float4*)&Ws[k][n4 * 4] = v;
        }
        __syncthreads();
        #pragma unroll
        for (int k0 = 0; k0 < 64; k0 += 4) {
            float4 av[4];
            #pragma unroll
            for (int i = 0; i < 4; i++) av[i] = *(const float4*)&As[ty * 4 + i][k0];
            #pragma unroll
            for (int kk = 0; kk < 4; kk++) {
                float4 w0 = *(const float4*)&Ws[k0 + kk][tx * 8];
                float4 w1 = *(const float4*)&Ws[k0 + kk][tx * 8 + 4];
                #pragma unroll
                for (int i = 0; i < 4; i++) {
                    float a = kk == 0 ? av[i].x : kk == 1 ? av[i].y : kk == 2 ? av[i].z : av[i].w;
                    acc[i][0] += a * w0.x; acc[i][1] += a * w0.y;
                    acc[i][2] += a * w0.z; acc[i][3] += a * w0.w;
                    acc[i][4] += a * w1.x; acc[i][5] += a * w1.y;
                    acc[i][6] += a * w1.z; acc[i][7] += a * w1.w;
                }
            }
        }
        __syncthreads();
    }
    float4 b0 = ((const float4*)bias)[tx * 2];
    float4 b1 = ((const float4*)bias)[tx * 2 + 1];
    float h[4][8];
    float s[4], q[4];
    #pragma unroll
    for (int i = 0; i < 4; i++) {
        h[i][0] = acc[i][0] + b0.x; h[i][1] = acc[i][1] + b0.y;
        h[i][2] = acc[i][2] + b0.z; h[i][3] = acc[i][3] + b0.w;
        h[i][4] = acc[i][4] + b1.x; h[i][5] = acc[i][5] + b1.y;
        h[i][6] = acc[i][6] + b1.z; h[i][7] = acc[i][7] + b1.w;
        float ls = 0.f, lq = 0.f;
        #pragma unroll
        for (int j = 0; j < 8; j++) { ls += h[i][j]; lq += h[i][j] * h[i][j]; }
        s[i] = ls; q[i] = lq;
    }
    #pragma unroll
    for (int m = 1; m < 16; m <<= 1) {
        #pragma unroll
        for (int i = 0; i < 4; i++) {
            s[i] += __shfl_xor(s[i], m, 16);
            q[i] += __shfl_xor(q[i], m, 16);
        }
    }
    float4 g0 = ((const float4*)lng)[tx * 2], g1 = ((const float4*)lng)[tx * 2 + 1];
    float4 e0 = ((const float4*)lnb)[tx * 2], e1 = ((const float4*)lnb)[tx * 2 + 1];
    #pragma unroll
    for (int i = 0; i < 4; i++) {
        float mu = s[i] * (1.f / 128.f);
        float var = q[i] * (1.f / 128.f) - mu * mu;
        float rs = rsqrtf(var + 1e-5f);
        int grow = row0 + ty * 4 + i;
        float4 x0 = ((float4*)x)[grow * 32 + tx * 2];
        float4 x1 = ((float4*)x)[grow * 32 + tx * 2 + 1];
        x0.x += (h[i][0] - mu) * rs * g0.x + e0.x;
        x0.y += (h[i][1] - mu) * rs * g0.y + e0.y;
        x0.z += (h[i][2] - mu) * rs * g0.z + e0.z;
        x0.w += (h[i][3] - mu) * rs * g0.w + e0.w;
        x1.x += (h[i][4] - mu) * rs * g1.x + e1.x;
        x1.y += (h[i][5] - mu) * rs * g1.y + e1.y;
        x1.z += (h[i][6] - mu) * rs * g1.z + e1.z;
        x1.w += (h[i][7] - mu) * rs * g1.w + e1.w;
        ((float4*)x)[grow * 32 + tx * 2] = x0;
        ((float4*)x)[grow * 32 + tx * 2 + 1] = x1;
    }
}

// ---------------- gate: LN(256) -> relu -> dot(gate_W2) ----------------
__global__ __launch_bounds__(256) void k_gate(const float* __restrict__ T,
                                              const float* __restrict__ lng,
                                              const float* __restrict__ lnb,
                                              const float* __restrict__ w2,
                                              const float* __restrict__ b2,
                                              float* __restrict__ gate) {
    int row = blockIdx.x * 4 + (threadIdx.x >> 6);
    int lane = threadIdx.x & 63;
    float4 v = ((const float4*)T)[row * 64 + lane];
    float s = v.x + v.y + v.z + v.w;
    float q = v.x * v.x + v.y * v.y + v.z * v.z + v.w * v.w;
    #pragma unroll
    for (int m = 1; m < 64; m <<= 1) { s += __shfl_xor(s, m); q += __shfl_xor(q, m); }
    float mu = s * (1.f / 256.f);
    float var = q * (1.f / 256.f) - mu * mu;
    float rs = rsqrtf(var + 1e-5f);
    float4 g4 = ((const float4*)lng)[lane];
    float4 e4 = ((const float4*)lnb)[lane];
    float4 w4 = ((const float4*)w2)[lane];
    float a = fmaxf((v.x - mu) * rs * g4.x + e4.x, 0.f) * w4.x
            + fmaxf((v.y - mu) * rs * g4.y + e4.y, 0.f) * w4.y
            + fmaxf((v.z - mu) * rs * g4.z + e4.z, 0.f) * w4.z
            + fmaxf((v.w - mu) * rs * g4.w + e4.w, 0.f) * w4.w;
    #pragma unroll
    for (int m = 1; m < 64; m <<= 1) a += __shfl_xor(a, m);
    if (lane == 0) gate[row] = a + b2[0];
}

// ---------------- attention pooling per graph ----------------
__global__ __launch_bounds__(256) void k_pool(const float* __restrict__ x,
                                              const float* __restrict__ gate,
                                              float* __restrict__ g) {
    __shared__ float sw[64];
    __shared__ float sacc[128];
    int b = blockIdx.x, tid = threadIdx.x;
    if (tid < 64) {
        float gv = gate[b * 64 + tid];
        float m = gv;
        #pragma unroll
        for (int mk = 1; mk < 64; mk <<= 1) m = fmaxf(m, __shfl_xor(m, mk));
        float e = expf(gv - m);
        float s = e;
        #pragma unroll
        for (int mk = 1; mk < 64; mk <<= 1) s += __shfl_xor(s, mk);
        sw[tid] = e / s;
    }
    __syncthreads();
    int d = tid & 127, h = tid >> 7;
    float acc = 0.f;
    for (int i = h * 32; i < h * 32 + 32; i++)
        acc += sw[i] * x[(b * 64 + i) * 128 + d];
    if (h == 0) sacc[d] = acc;
    __syncthreads();
    if (h == 1) g[b * 128 + d] = sacc[d] + acc;
}

// ---------------- residual blocks + head, one block per graph ----------------
__global__ __launch_bounds__(128) void k_tail(const float* __restrict__ g_in,
        const float* __restrict__ fc1W, const float* __restrict__ fc1b,
        const float* __restrict__ ln1g, const float* __restrict__ ln1b,
        const float* __restrict__ fc2W, const float* __restrict__ fc2b,
        const float* __restrict__ ln2g, const float* __restrict__ ln2b,
        const float* __restrict__ pW1, const float* __restrict__ pb1,
        const float* __restrict__ pW2, const float* __restrict__ pb2,
        float* __restrict__ out) {
    __shared__ float sg[128], sh[128];
    __shared__ float ps[2], pq[2];
    int b = blockIdx.x, tid = threadIdx.x;
    int w = tid >> 6;
    sg[tid] = g_in[b * 128 + tid];
    __syncthreads();
    for (int r = 0; r < 2; r++) {
        const float* W1 = fc1W + r * 16384;
        float acc = fc1b[r * 128 + tid];
        for (int k = 0; k < 128; k++) acc += sg[k] * W1[k * 128 + tid];
        float s = acc, q = acc * acc;
        #pragma unroll
        for (int m = 1; m < 64; m <<= 1) { s += __shfl_xor(s, m); q += __shfl_xor(q, m); }
        __syncthreads();
        if ((tid & 63) == 0) { ps[w] = s; pq[w] = q; }
        __syncthreads();
        float S = ps[0] + ps[1], Q = pq[0] + pq[1];
        float mu = S * (1.f / 128.f);
        float var = Q * (1.f / 128.f) - mu * mu;
        float z = (acc - mu) * rsqrtf(var + 1e-5f) * ln1g[r * 128 + tid] + ln1b[r * 128 + tid];
        z = gelu_exact(z);
        __syncthreads();
        sh[tid] = z;
        __syncthreads();
        const float* W2 = fc2W + r * 16384;
        float acc2 = fc2b[r * 128 + tid];
        for (int k = 0; k < 128; k++) acc2 += sh[k] * W2[k * 128 + tid];
        s = acc2; q = acc2 * acc2;
        #pragma unroll
        for (int m = 1; m < 64; m <<= 1) { s += __shfl_xor(s, m); q += __shfl_xor(q, m); }
        __syncthreads();
        if ((tid & 63) == 0) { ps[w] = s; pq[w] = q; }
        __syncthreads();
        S = ps[0] + ps[1]; Q = pq[0] + pq[1];
        mu = S * (1.f / 128.f);
        var = Q * (1.f / 128.f) - mu * mu;
        float z2 = (acc2 - mu) * rsqrtf(var + 1e-5f) * ln2g[r * 128 + tid] + ln2b[r * 128 + tid];
        __syncthreads();
        sg[tid] = sg[tid] + z2;
        __syncthreads();
    }
    float acc = pb1[tid];
    for (int k = 0; k < 128; k++) acc += sg[k] * pW1[k * 128 + tid];
    __syncthreads();
    sh[tid] = gelu_exact(acc);
    __syncthreads();
    if (tid < 12) {
        float o = pb2[tid];
        for (int k = 0; k < 128; k++) o += sh[k] * pW2[k * 12 + tid];
        out[b * 12 + tid] = o;
    }
}

// ---------------- launch ----------------
extern "C" void kernel_launch(void* const* d_in, const int* in_sizes, int n_in,
                              void* d_out, int out_size, void* d_ws, size_t ws_size,
                              hipStream_t stream) {
    const float* logits    = (const float*)d_in[0];
    const int*   atom_feat = (const int*)d_in[2];
    const int*   edge_src  = (const int*)d_in[3];
    const int*   edge_dst  = edge_src + N_EDGES;
    const int*   edge_attr = (const int*)d_in[4];
    const float* atom_emb  = (const float*)d_in[6];
    const float* edge_emb  = (const float*)d_in[7];
    const float* gnn_W1    = (const float*)d_in[8];
    const float* gnn_b1    = (const float*)d_in[9];
    const float* gnn_W2    = (const float*)d_in[10];
    const float* gnn_b2    = (const float*)d_in[11];
    const float* gnn_ln_g  = (const float*)d_in[12];
    const float* gnn_ln_b  = (const float*)d_in[13];
    const float* gate_W1   = (const float*)d_in[14];
    const float* gate_b1   = (const float*)d_in[15];
    const float* gate_ln_g = (const float*)d_in[16];
    const float* gate_ln_b = (const float*)d_in[17];
    const float* gate_W2   = (const float*)d_in[18];
    const float* gate_b2   = (const float*)d_in[19];
    const float* res_fc1_W = (const float*)d_in[20];
    const float* res_fc1_b = (const float*)d_in[21];
    const float* res_ln1_g = (const float*)d_in[22];
    const float* res_ln1_b = (const float*)d_in[23];
    const float* res_fc2_W = (const float*)d_in[24];
    const float* res_fc2_b = (const float*)d_in[25];
    const float* res_ln2_g = (const float*)d_in[26];
    const float* res_ln2_b = (const float*)d_in[27];
    const float* pred_W1   = (const float*)d_in[28];
    const float* pred_b1   = (const float*)d_in[29];
    const float* pred_W2   = (const float*)d_in[30];
    const float* pred_b2   = (const float*)d_in[31];
    float* out = (float*)d_out;

    char* w = (char*)d_ws;
    float* x      = (float*)w; w += (size_t)N_NODES * 128 * 4;   // 16 MB
    float* agg    = (float*)w; w += (size_t)N_NODES * 128 * 4;   // 16 MB
    float* t      = (float*)w; w += (size_t)N_NODES * 256 * 4;   // 32 MB
    int*   deg    = (int*)w;   w += N_NODES * 4;
    int*   offs   = (int*)w;   w += (N_NODES + 64) * 4;
    int*   cursor = (int*)w;   w += N_NODES * 4;
    int*   csr    = (int*)w;   w += N_EDGES * 4;
    float* gate   = (float*)w; w += N_NODES * 4;
    float* gpool  = (float*)w; w += B_GRAPHS * 128 * 4;

    // CSR build (once; reused across the 3 layers)
    k_zero<<<N_NODES / 256, 256, 0, stream>>>(deg, N_NODES);
    k_deg<<<N_EDGES / 256, 256, 0, stream>>>(edge_dst, deg);
    k_scan<<<1, 1024, 0, stream>>>(deg, offs, cursor);
    k_scatter<<<N_EDGES / 256, 256, 0, stream>>>(edge_src, edge_dst, edge_attr, cursor, csr);

    // x = logits[mask] + atom_emb[feat]
    k_build_x<<<N_NODES * 32 / 256, 256, 0, stream>>>(logits, atom_feat, atom_emb, x);

    // 3 GNN layers
    for (int l = 0; l < 3; l++) {
        k_agg<<<N_NODES / 4, 256, 0, stream>>>(x, offs, csr, edge_emb, agg);
        k_gemm1<<<dim3(4, N_NODES / 64), 256, 0, stream>>>(
            agg, gnn_W1 + l * 32768, gnn_b1 + l * 256, t, 1);
        k_gemm2<<<N_NODES / 64, 256, 0, stream>>>(
            t, gnn_W2 + l * 32768, gnn_b2 + l * 128,
            gnn_ln_g + l * 128, gnn_ln_b + l * 128, x);
    }

    // gate logits
    k_gemm1<<<dim3(4, N_NODES / 64), 256, 0, stream>>>(x, gate_W1, gate_b1, t, 0);
    k_gate<<<N_NODES / 4, 256, 0, stream>>>(t, gate_ln_g, gate_ln_b, gate_W2, gate_b2, gate);

    // attention pooling
    k_pool<<<B_GRAPHS, 256, 0, stream>>>(x, gate, gpool);

    // residual blocks + head
    k_tail<<<B_GRAPHS, 128, 0, stream>>>(gpool,
        res_fc1_W, res_fc1_b, res_ln1_g, res_ln1_b,
        res_fc2_W, res_fc2_b, res_ln2_g, res_ln2_b,
        pred_W1, pred_b1, pred_W2, pred_b2, out);
}

// Round 2
// 533.440 us; speedup vs baseline: 4.0512x; 4.0512x over previous
//
#include <hip/hip_runtime.h>
#include <hip/hip_bf16.h>

#define N_NODES 32768
#define N_EDGES 524288
#define DD 128
#define B_GRAPHS 512

// ---------------- utility ----------------
__device__ __forceinline__ float gelu_exact(float z) {
    return 0.5f * z * (1.0f + erff(z * 0.70710678118654752440f));
}

// ---------------- CSR build ----------------
__global__ void k_zero(int* __restrict__ p, int n) {
    int i = blockIdx.x * blockDim.x + threadIdx.x;
    if (i < n) p[i] = 0;
}

__global__ void k_deg(const int* __restrict__ dst, int* __restrict__ deg) {
    int e = blockIdx.x * blockDim.x + threadIdx.x;
    if (e < N_EDGES) atomicAdd(&deg[dst[e]], 1);
}

__global__ __launch_bounds__(1024) void k_scan(const int* __restrict__ deg,
                                               int* __restrict__ offs,
                                               int* __restrict__ cursor) {
    int tid = threadIdx.x;
    int lane = tid & 63, wid = tid >> 6;
    int base = tid * 32;
    int pref[32];
    int run = 0;
    #pragma unroll
    for (int i = 0; i < 32; i++) { pref[i] = run; run += deg[base + i]; }
    int s = run;
    for (int m = 1; m < 64; m <<= 1) { int t = __shfl_up(s, m); if (lane >= m) s += t; }
    __shared__ int wsum[16];
    if (lane == 63) wsum[wid] = s;
    __syncthreads();
    if (tid < 16) {
        int v = wsum[tid];
        for (int m = 1; m < 16; m <<= 1) { int t = __shfl_up(v, m, 16); if (tid >= m) v += t; }
        wsum[tid] = v;
    }
    __syncthreads();
    int wbase = wid ? wsum[wid - 1] : 0;
    int ebase = wbase + (s - run);        // exclusive prefix for this thread
    #pragma unroll
    for (int i = 0; i < 32; i++) {
        int o = ebase + pref[i];
        offs[base + i] = o;
        cursor[base + i] = o;
    }
    if (tid == 1023) offs[N_NODES] = ebase + run;
}

__global__ void k_scatter(const int* __restrict__ src, const int* __restrict__ dst,
                          const int* __restrict__ attr, int* __restrict__ cursor,
                          int* __restrict__ csr) {
    int e = blockIdx.x * blockDim.x + threadIdx.x;
    if (e < N_EDGES) {
        int p = atomicAdd(&cursor[dst[e]], 1);
        csr[p] = src[e] | (attr[e] << 16);
    }
}

// ---------------- x init: masked gather + atom embedding ----------------
__global__ void k_build_x(const float* __restrict__ logits, const int* __restrict__ feat,
                          const float* __restrict__ aemb, float* __restrict__ x) {
    int idx = blockIdx.x * blockDim.x + threadIdx.x;   // float4 id, N_NODES*32 total
    int n = idx >> 5, c = idx & 31;
    int srow = ((n >> 6) << 7) + (n & 63);             // analytic nonzero(mask) index
    float4 lv = ((const float4*)logits)[srow * 32 + c];
    float4 av = ((const float4*)aemb)[feat[n] * 32 + c];
    float4 o;
    o.x = lv.x + av.x; o.y = lv.y + av.y; o.z = lv.z + av.z; o.w = lv.w + av.w;
    ((float4*)x)[idx] = o;
}

// ---------------- per-node aggregation (atomic-free via CSR) ----------------
__global__ __launch_bounds__(256) void k_agg(const float* __restrict__ x,
                                             const int* __restrict__ offs,
                                             const int* __restrict__ csr,
                                             const float* __restrict__ eemb,
                                             float* __restrict__ agg) {
    __shared__ float semb[8 * 128];
    int tid = threadIdx.x;
    for (int i = tid; i < 1024; i += 256) semb[i] = eemb[i];
    __syncthreads();
    int node = blockIdx.x * 4 + (tid >> 6);
    int lane = tid & 63;
    int o0 = offs[node], o1 = offs[node + 1];
    float2 acc = make_float2(0.f, 0.f);
    for (int e = o0; e < o1; e++) {
        int pk = csr[e];
        int s = pk & 0xFFFF, a = pk >> 16;
        float2 xv = *(const float2*)&x[s * 128 + lane * 2];
        float2 ev = *(const float2*)&semb[a * 128 + lane * 2];
        acc.x += fmaxf(xv.x + ev.x, 0.f);
        acc.y += fmaxf(xv.y + ev.y, 0.f);
    }
    *(float2*)&agg[node * 128 + lane * 2] = acc;
}

// ---------------- shared GEMM core ----------------
// C_tile[64,128] = A[row0:row0+64, 0:K] @ W[0:K, n0:n0+128]
// 256 threads, 4x8 thread tile (tx = tid&15 -> 8 cols, ty = tid>>4 -> 4 rows).
// BK=64 staging; #pragma unroll 2 on the k-group loop keeps register pressure
// bounded (full unroll previously caused ~1.4 GB/dispatch of scratch spill
// round-trips: FETCH==WRITE==740 MB, VGPR_Count=256, VALUBusy 6.7%).
__device__ __forceinline__ void gemm_core(const float* __restrict__ A,
                                          const float* __restrict__ W,
                                          int K, int NC, int row0, int n0, int tid,
                                          float (&acc)[4][8],
                                          float (&As)[64][68], float (&Ws)[64][132]) {
    int tx = tid & 15, ty = tid >> 4;
    int nst = K >> 6;
    for (int st = 0; st < nst; ++st) {
        if (st) __syncthreads();   // protect LDS from overwrite while prev stage computes
        #pragma unroll
        for (int j = 0; j < 4; ++j) {
            int lin = tid + j * 256;
            int k4 = lin & 15, m = lin >> 4;
            *(float4*)&As[m][k4 * 4] = ((const float4*)A)[(row0 + m) * (K >> 2) + st * 16 + k4];
        }
        #pragma unroll
        for (int j = 0; j < 8; ++j) {
            int lin = tid + j * 256;
            int n4 = lin & 31, k = lin >> 5;
            *(float4*)&Ws[k][n4 * 4] = ((const float4*)W)[(st * 64 + k) * (NC >> 2) + (n0 >> 2) + n4];
        }
        __syncthreads();
        #pragma unroll 2
        for (int k0 = 0; k0 < 64; k0 += 4) {
            float4 av[4];
            #pragma unroll
            for (int i = 0; i < 4; ++i) av[i] = *(const float4*)&As[ty * 4 + i][k0];
            #pragma unroll
            for (int kk = 0; kk < 4; ++kk) {
                float4 w0 = *(const float4*)&Ws[k0 + kk][tx * 8];
                float4 w1 = *(const float4*)&Ws[k0 + kk][tx * 8 + 4];
                #pragma unroll
                for (int i = 0; i < 4; ++i) {
                    float a = kk == 0 ? av[i].x : kk == 1 ? av[i].y : kk == 2 ? av[i].z : av[i].w;
                    acc[i][0] += a * w0.x; acc[i][1] += a * w0.y;
                    acc[i][2] += a * w0.z; acc[i][3] += a * w0.w;
                    acc[i][4] += a * w1.x; acc[i][5] += a * w1.y;
                    acc[i][6] += a * w1.z; acc[i][7] += a * w1.w;
                }
            }
        }
    }
}

// ---------------- GEMM1: C[32768,NC=256] = act(A[32768,K] @ W[K,256] + b) ----------------
__global__ __launch_bounds__(256, 4) void k_gemm1(const float* __restrict__ A,
                                                  const float* __restrict__ W,
                                                  const float* __restrict__ bias,
                                                  float* __restrict__ C,
                                                  int K, int relu) {
    __shared__ float As[64][68];
    __shared__ float Ws[64][132];
    int tid = threadIdx.x;
    int row0 = blockIdx.y * 64, n0 = blockIdx.x * 128;
    float acc[4][8] = {};
    gemm_core(A, W, K, 256, row0, n0, tid, acc, As, Ws);
    int tx = tid & 15, ty = tid >> 4;
    float4 b0 = ((const float4*)bias)[(n0 >> 2) + tx * 2];
    float4 b1 = ((const float4*)bias)[(n0 >> 2) + tx * 2 + 1];
    #pragma unroll
    for (int i = 0; i < 4; ++i) {
        float4 o0, o1;
        o0.x = acc[i][0] + b0.x; o0.y = acc[i][1] + b0.y;
        o0.z = acc[i][2] + b0.z; o0.w = acc[i][3] + b0.w;
        o1.x = acc[i][4] + b1.x; o1.y = acc[i][5] + b1.y;
        o1.z = acc[i][6] + b1.z; o1.w = acc[i][7] + b1.w;
        if (relu) {
            o0.x = fmaxf(o0.x, 0.f); o0.y = fmaxf(o0.y, 0.f);
            o0.z = fmaxf(o0.z, 0.f); o0.w = fmaxf(o0.w, 0.f);
            o1.x = fmaxf(o1.x, 0.f); o1.y = fmaxf(o1.y, 0.f);
            o1.z = fmaxf(o1.z, 0.f); o1.w = fmaxf(o1.w, 0.f);
        }
        ((float4*)C)[(row0 + ty * 4 + i) * 64 + (n0 >> 2) + tx * 2] = o0;
        ((float4*)C)[(row0 + ty * 4 + i) * 64 + (n0 >> 2) + tx * 2 + 1] = o1;
    }
}

// ---------------- GEMM2 + LN + residual: x += LN(T[32768,256] @ W[256,128] + b) ----------------
__global__ __launch_bounds__(256, 4) void k_gemm2(const float* __restrict__ T,
                                                  const float* __restrict__ W,
                                                  const float* __restrict__ bias,
                                                  const float* __restrict__ lng,
                                                  const float* __restrict__ lnb,
                                                  float* __restrict__ x) {
    __shared__ float As[64][68];
    __shared__ float Ws[64][132];
    int tid = threadIdx.x;
    int row0 = blockIdx.x * 64;
    float acc[4][8] = {};
    gemm_core(T, W, 256, 128, row0, 0, tid, acc, As, Ws);
    int tx = tid & 15, ty = tid >> 4;
    float4 b0 = ((const float4*)bias)[tx * 2];
    float4 b1 = ((const float4*)bias)[tx * 2 + 1];
    float h[4][8];
    float s[4], q[4];
    #pragma unroll
    for (int i = 0; i < 4; i++) {
        h[i][0] = acc[i][0] + b0.x; h[i][1] = acc[i][1] + b0.y;
        h[i][2] = acc[i][2] + b0.z; h[i][3] = acc[i][3] + b0.w;
        h[i][4] = acc[i][4] + b1.x; h[i][5] = acc[i][5] + b1.y;
        h[i][6] = acc[i][6] + b1.z; h[i][7] = acc[i][7] + b1.w;
        float ls = 0.f, lq = 0.f;
        #pragma unroll
        for (int j = 0; j < 8; j++) { ls += h[i][j]; lq += h[i][j] * h[i][j]; }
        s[i] = ls; q[i] = lq;
    }
    #pragma unroll
    for (int m = 1; m < 16; m <<= 1) {
        #pragma unroll
        for (int i = 0; i < 4; i++) {
            s[i] += __shfl_xor(s[i], m, 16);
            q[i] += __shfl_xor(q[i], m, 16);
        }
    }
    float4 g0 = ((const float4*)lng)[tx * 2], g1 = ((const float4*)lng)[tx * 2 + 1];
    float4 e0 = ((const float4*)lnb)[tx * 2], e1 = ((const float4*)lnb)[tx * 2 + 1];
    #pragma unroll
    for (int i = 0; i < 4; i++) {
        float mu = s[i] * (1.f / 128.f);
        float var = q[i] * (1.f / 128.f) - mu * mu;
        float rs = rsqrtf(var + 1e-5f);
        int grow = row0 + ty * 4 + i;
        float4 x0 = ((float4*)x)[grow * 32 + tx * 2];
        float4 x1 = ((float4*)x)[grow * 32 + tx * 2 + 1];
        x0.x += (h[i][0] - mu) * rs * g0.x + e0.x;
        x0.y += (h[i][1] - mu) * rs * g0.y + e0.y;
        x0.z += (h[i][2] - mu) * rs * g0.z + e0.z;
        x0.w += (h[i][3] - mu) * rs * g0.w + e0.w;
        x1.x += (h[i][4] - mu) * rs * g1.x + e1.x;
        x1.y += (h[i][5] - mu) * rs * g1.y + e1.y;
        x1.z += (h[i][6] - mu) * rs * g1.z + e1.z;
        x1.w += (h[i][7] - mu) * rs * g1.w + e1.w;
        ((float4*)x)[grow * 32 + tx * 2] = x0;
        ((float4*)x)[grow * 32 + tx * 2 + 1] = x1;
    }
}

// ---------------- gate: LN(256) -> relu -> dot(gate_W2) ----------------
__global__ __launch_bounds__(256) void k_gate(const float* __restrict__ T,
                                              const float* __restrict__ lng,
                                              const float* __restrict__ lnb,
                                              const float* __restrict__ w2,
                                              const float* __restrict__ b2,
                                              float* __restrict__ gate) {
    int row = blockIdx.x * 4 + (threadIdx.x >> 6);
    int lane = threadIdx.x & 63;
    float4 v = ((const float4*)T)[row * 64 + lane];
    float s = v.x + v.y + v.z + v.w;
    float q = v.x * v.x + v.y * v.y + v.z * v.z + v.w * v.w;
    #pragma unroll
    for (int m = 1; m < 64; m <<= 1) { s += __shfl_xor(s, m); q += __shfl_xor(q, m); }
    float mu = s * (1.f / 256.f);
    float var = q * (1.f / 256.f) - mu * mu;
    float rs = rsqrtf(var + 1e-5f);
    float4 g4 = ((const float4*)lng)[lane];
    float4 e4 = ((const float4*)lnb)[lane];
    float4 w4 = ((const float4*)w2)[lane];
    float a = fmaxf((v.x - mu) * rs * g4.x + e4.x, 0.f) * w4.x
            + fmaxf((v.y - mu) * rs * g4.y + e4.y, 0.f) * w4.y
            + fmaxf((v.z - mu) * rs * g4.z + e4.z, 0.f) * w4.z
            + fmaxf((v.w - mu) * rs * g4.w + e4.w, 0.f) * w4.w;
    #pragma unroll
    for (int m = 1; m < 64; m <<= 1) a += __shfl_xor(a, m);
    if (lane == 0) gate[row] = a + b2[0];
}

// ---------------- attention pooling per graph ----------------
__global__ __launch_bounds__(256) void k_pool(const float* __restrict__ x,
                                              const float* __restrict__ gate,
                                              float* __restrict__ g) {
    __shared__ float sw[64];
    __shared__ float sacc[128];
    int b = blockIdx.x, tid = threadIdx.x;
    if (tid < 64) {
        float gv = gate[b * 64 + tid];
        float m = gv;
        #pragma unroll
        for (int mk = 1; mk < 64; mk <<= 1) m = fmaxf(m, __shfl_xor(m, mk));
        float e = expf(gv - m);
        float s = e;
        #pragma unroll
        for (int mk = 1; mk < 64; mk <<= 1) s += __shfl_xor(s, mk);
        sw[tid] = e / s;
    }
    __syncthreads();
    int d = tid & 127, h = tid >> 7;
    float acc = 0.f;
    for (int i = h * 32; i < h * 32 + 32; i++)
        acc += sw[i] * x[(b * 64 + i) * 128 + d];
    if (h == 0) sacc[d] = acc;
    __syncthreads();
    if (h == 1) g[b * 128 + d] = sacc[d] + acc;
}

// ---------------- residual blocks + head, one block per graph ----------------
__global__ __launch_bounds__(128) void k_tail(const float* __restrict__ g_in,
        const float* __restrict__ fc1W, const float* __restrict__ fc1b,
        const float* __restrict__ ln1g, const float* __restrict__ ln1b,
        const float* __restrict__ fc2W, const float* __restrict__ fc2b,
        const float* __restrict__ ln2g, const float* __restrict__ ln2b,
        const float* __restrict__ pW1, const float* __restrict__ pb1,
        const float* __restrict__ pW2, const float* __restrict__ pb2,
        float* __restrict__ out) {
    __shared__ float sg[128], sh[128];
    __shared__ float ps[2], pq[2];
    int b = blockIdx.x, tid = threadIdx.x;
    int w = tid >> 6;
    sg[tid] = g_in[b * 128 + tid];
    __syncthreads();
    for (int r = 0; r < 2; r++) {
        const float* W1 = fc1W + r * 16384;
        float acc = fc1b[r * 128 + tid];
        for (int k = 0; k < 128; k++) acc += sg[k] * W1[k * 128 + tid];
        float s = acc, q = acc * acc;
        #pragma unroll
        for (int m = 1; m < 64; m <<= 1) { s += __shfl_xor(s, m); q += __shfl_xor(q, m); }
        __syncthreads();
        if ((tid & 63) == 0) { ps[w] = s; pq[w] = q; }
        __syncthreads();
        float S = ps[0] + ps[1], Q = pq[0] + pq[1];
        float mu = S * (1.f / 128.f);
        float var = Q * (1.f / 128.f) - mu * mu;
        float z = (acc - mu) * rsqrtf(var + 1e-5f) * ln1g[r * 128 + tid] + ln1b[r * 128 + tid];
        z = gelu_exact(z);
        __syncthreads();
        sh[tid] = z;
        __syncthreads();
        const float* W2 = fc2W + r * 16384;
        float acc2 = fc2b[r * 128 + tid];
        for (int k = 0; k < 128; k++) acc2 += sh[k] * W2[k * 128 + tid];
        s = acc2; q = acc2 * acc2;
        #pragma unroll
        for (int m = 1; m < 64; m <<= 1) { s += __shfl_xor(s, m); q += __shfl_xor(q, m); }
        __syncthreads();
        if ((tid & 63) == 0) { ps[w] = s; pq[w] = q; }
        __syncthreads();
        S = ps[0] + ps[1]; Q = pq[0] + pq[1];
        mu = S * (1.f / 128.f);
        var = Q * (1.f / 128.f) - mu * mu;
        float z2 = (acc2 - mu) * rsqrtf(var + 1e-5f) * ln2g[r * 128 + tid] + ln2b[r * 128 + tid];
        __syncthreads();
        sg[tid] = sg[tid] + z2;
        __syncthreads();
    }
    float acc = pb1[tid];
    for (int k = 0; k < 128; k++) acc += sg[k] * pW1[k * 128 + tid];
    __syncthreads();
    sh[tid] = gelu_exact(acc);
    __syncthreads();
    if (tid < 12) {
        float o = pb2[tid];
        for (int k = 0; k < 128; k++) o += sh[k] * pW2[k * 12 + tid];
        out[b * 12 + tid] = o;
    }
}

// ---------------- launch ----------------
extern "C" void kernel_launch(void* const* d_in, const int* in_sizes, int n_in,
                              void* d_out, int out_size, void* d_ws, size_t ws_size,
                              hipStream_t stream) {
    const float* logits    = (const float*)d_in[0];
    const int*   atom_feat = (const int*)d_in[2];
    const int*   edge_src  = (const int*)d_in[3];
    const int*   edge_dst  = edge_src + N_EDGES;
    const int*   edge_attr = (const int*)d_in[4];
    const float* atom_emb  = (const float*)d_in[6];
    const float* edge_emb  = (const float*)d_in[7];
    const float* gnn_W1    = (const float*)d_in[8];
    const float* gnn_b1    = (const float*)d_in[9];
    const float* gnn_W2    = (const float*)d_in[10];
    const float* gnn_b2    = (const float*)d_in[11];
    const float* gnn_ln_g  = (const float*)d_in[12];
    const float* gnn_ln_b  = (const float*)d_in[13];
    const float* gate_W1   = (const float*)d_in[14];
    const float* gate_b1   = (const float*)d_in[15];
    const float* gate_ln_g = (const float*)d_in[16];
    const float* gate_ln_b = (const float*)d_in[17];
    const float* gate_W2   = (const float*)d_in[18];
    const float* gate_b2   = (const float*)d_in[19];
    const float* res_fc1_W = (const float*)d_in[20];
    const float* res_fc1_b = (const float*)d_in[21];
    const float* res_ln1_g = (const float*)d_in[22];
    const float* res_ln1_b = (const float*)d_in[23];
    const float* res_fc2_W = (const float*)d_in[24];
    const float* res_fc2_b = (const float*)d_in[25];
    const float* res_ln2_g = (const float*)d_in[26];
    const float* res_ln2_b = (const float*)d_in[27];
    const float* pred_W1   = (const float*)d_in[28];
    const float* pred_b1   = (const float*)d_in[29];
    const float* pred_W2   = (const float*)d_in[30];
    const float* pred_b2   = (const float*)d_in[31];
    float* out = (float*)d_out;

    char* w = (char*)d_ws;
    float* x      = (float*)w; w += (size_t)N_NODES * 128 * 4;   // 16 MB
    float* agg    = (float*)w; w += (size_t)N_NODES * 128 * 4;   // 16 MB
    float* t      = (float*)w; w += (size_t)N_NODES * 256 * 4;   // 32 MB
    int*   deg    = (int*)w;   w += N_NODES * 4;
    int*   offs   = (int*)w;   w += (N_NODES + 64) * 4;
    int*   cursor = (int*)w;   w += N_NODES * 4;
    int*   csr    = (int*)w;   w += N_EDGES * 4;
    float* gate   = (float*)w; w += N_NODES * 4;
    float* gpool  = (float*)w; w += B_GRAPHS * 128 * 4;

    // CSR build (once; reused across the 3 layers)
    k_zero<<<N_NODES / 256, 256, 0, stream>>>(deg, N_NODES);
    k_deg<<<N_EDGES / 256, 256, 0, stream>>>(edge_dst, deg);
    k_scan<<<1, 1024, 0, stream>>>(deg, offs, cursor);
    k_scatter<<<N_EDGES / 256, 256, 0, stream>>>(edge_src, edge_dst, edge_attr, cursor, csr);

    // x = logits[mask] + atom_emb[feat]
    k_build_x<<<N_NODES * 32 / 256, 256, 0, stream>>>(logits, atom_feat, atom_emb, x);

    // 3 GNN layers
    for (int l = 0; l < 3; l++) {
        k_agg<<<N_NODES / 4, 256, 0, stream>>>(x, offs, csr, edge_emb, agg);
        k_gemm1<<<dim3(2, N_NODES / 64), 256, 0, stream>>>(
            agg, gnn_W1 + l * 32768, gnn_b1 + l * 256, t, 128, 1);
        k_gemm2<<<N_NODES / 64, 256, 0, stream>>>(
            t, gnn_W2 + l * 32768, gnn_b2 + l * 128,
            gnn_ln_g + l * 128, gnn_ln_b + l * 128, x);
    }

    // gate logits
    k_gemm1<<<dim3(2, N_NODES / 64), 256, 0, stream>>>(x, gate_W1, gate_b1, t, 128, 0);
    k_gate<<<N_NODES / 4, 256, 0, stream>>>(t, gate_ln_g, gate_ln_b, gate_W2, gate_b2, gate);

    // attention pooling
    k_pool<<<B_GRAPHS, 256, 0, stream>>>(x, gate, gpool);

    // residual blocks + head
    k_tail<<<B_GRAPHS, 128, 0, stream>>>(gpool,
        res_fc1_W, res_fc1_b, res_ln1_g, res_ln1_b,
        res_fc2_W, res_fc2_b, res_ln2_g, res_ln2_b,
        pred_W1, pred_b1, pred_W2, pred_b2, out);
}

// Round 3
// 319.990 us; speedup vs baseline: 6.7536x; 1.6671x over previous
//
#include <hip/hip_runtime.h>
#include <hip/hip_bf16.h>

#define N_NODES 32768
#define N_EDGES 524288
#define B_GRAPHS 512

typedef __attribute__((ext_vector_type(8))) short sh8;    // 8 bf16 (4 VGPR) MFMA operand
typedef __attribute__((ext_vector_type(4))) float f32x4;  // MFMA accumulator

// ---------------- bf16 helpers (RNE, exact widen) ----------------
__device__ __forceinline__ unsigned short f2b(float f) {
    unsigned int u = __float_as_uint(f);
    return (unsigned short)((u + 0x7FFFu + ((u >> 16) & 1u)) >> 16);
}
__device__ __forceinline__ float gelu_exact(float z) {
    return 0.5f * z * (1.0f + erff(z * 0.70710678118654752440f));
}

// ---------------- weight prep: transpose + fp32->bf16 ----------------
// W1[3][128][256] -> W1T[3][256][128]; W2[3][256][128] -> W2T[3][128][256];
// gate_W1[128][256] -> gW1T[256][128]
__global__ __launch_bounds__(256) void k_prep(const float* __restrict__ W1,
                                              const float* __restrict__ W2,
                                              const float* __restrict__ gW1,
                                              unsigned short* __restrict__ W1T,
                                              unsigned short* __restrict__ W2T,
                                              unsigned short* __restrict__ gW1T) {
    int tid = blockIdx.x * 256 + threadIdx.x;   // 7*32768 total
    int m = tid >> 15, i = tid & 32767;
    if (m < 3) {
        int r = i >> 8, c = i & 255;
        W1T[m * 32768 + c * 128 + r] = f2b(W1[m * 32768 + i]);
    } else if (m < 6) {
        int mm = m - 3;
        int r = i >> 7, c = i & 127;
        W2T[mm * 32768 + c * 256 + r] = f2b(W2[mm * 32768 + i]);
    } else {
        int r = i >> 8, c = i & 255;
        gW1T[c * 128 + r] = f2b(gW1[i]);
    }
}

// ---------------- CSR build ----------------
__global__ void k_zero(int* __restrict__ p, int n) {
    int i = blockIdx.x * blockDim.x + threadIdx.x;
    if (i < n) p[i] = 0;
}

__global__ void k_deg(const int* __restrict__ dst, int* __restrict__ deg) {
    int e = blockIdx.x * blockDim.x + threadIdx.x;
    if (e < N_EDGES) atomicAdd(&deg[dst[e]], 1);
}

__global__ __launch_bounds__(1024) void k_scan(const int* __restrict__ deg,
                                               int* __restrict__ offs,
                                               int* __restrict__ cursor) {
    int tid = threadIdx.x;
    int lane = tid & 63, wid = tid >> 6;
    int base = tid * 32;
    int pref[32];
    int run = 0;
    #pragma unroll
    for (int i = 0; i < 32; i++) { pref[i] = run; run += deg[base + i]; }
    int s = run;
    for (int m = 1; m < 64; m <<= 1) { int t = __shfl_up(s, m); if (lane >= m) s += t; }
    __shared__ int wsum[16];
    if (lane == 63) wsum[wid] = s;
    __syncthreads();
    if (tid < 16) {
        int v = wsum[tid];
        for (int m = 1; m < 16; m <<= 1) { int t = __shfl_up(v, m, 16); if (tid >= m) v += t; }
        wsum[tid] = v;
    }
    __syncthreads();
    int wbase = wid ? wsum[wid - 1] : 0;
    int ebase = wbase + (s - run);
    #pragma unroll
    for (int i = 0; i < 32; i++) {
        int o = ebase + pref[i];
        offs[base + i] = o;
        cursor[base + i] = o;
    }
    if (tid == 1023) offs[N_NODES] = ebase + run;
}

__global__ void k_scatter(const int* __restrict__ src, const int* __restrict__ dst,
                          const int* __restrict__ attr, int* __restrict__ cursor,
                          int* __restrict__ csr) {
    int e = blockIdx.x * blockDim.x + threadIdx.x;
    if (e < N_EDGES) {
        int p = atomicAdd(&cursor[dst[e]], 1);
        csr[p] = src[e] | (attr[e] << 16);
    }
}

// ---------------- x init: masked gather + atom embedding (fp32 master + bf16 shadow) ----------------
__global__ void k_build_x(const float* __restrict__ logits, const int* __restrict__ feat,
                          const float* __restrict__ aemb, float* __restrict__ x,
                          unsigned short* __restrict__ xb) {
    int idx = blockIdx.x * blockDim.x + threadIdx.x;   // float4 id, N_NODES*32 total
    int n = idx >> 5, c = idx & 31;
    int srow = ((n >> 6) << 7) + (n & 63);             // analytic nonzero(mask) index
    float4 lv = ((const float4*)logits)[srow * 32 + c];
    float4 av = ((const float4*)aemb)[feat[n] * 32 + c];
    float4 o;
    o.x = lv.x + av.x; o.y = lv.y + av.y; o.z = lv.z + av.z; o.w = lv.w + av.w;
    ((float4*)x)[idx] = o;
    ushort4 ob;
    ob.x = f2b(o.x); ob.y = f2b(o.y); ob.z = f2b(o.z); ob.w = f2b(o.w);
    ((ushort4*)xb)[idx] = ob;
}

// ---------------- per-node aggregation: bf16 gathers, 4-edge unrolled ----------------
__global__ __launch_bounds__(256) void k_agg(const unsigned short* __restrict__ xb,
                                             const int* __restrict__ offs,
                                             const int* __restrict__ csr,
                                             const float* __restrict__ eemb,
                                             unsigned short* __restrict__ aggb) {
    __shared__ float semb[8 * 128];
    int tid = threadIdx.x;
    for (int i = tid; i < 1024; i += 256) semb[i] = eemb[i];
    __syncthreads();
    int node = blockIdx.x * 4 + (tid >> 6);
    int lane = tid & 63;
    int o0 = offs[node], o1 = offs[node + 1];
    float ax = 0.f, ay = 0.f;
    int e = o0;
    for (; e + 3 < o1; e += 4) {
        int p0 = csr[e], p1 = csr[e + 1], p2 = csr[e + 2], p3 = csr[e + 3];
        unsigned int u0 = *(const unsigned int*)(xb + (size_t)(p0 & 0xFFFF) * 128 + lane * 2);
        unsigned int u1 = *(const unsigned int*)(xb + (size_t)(p1 & 0xFFFF) * 128 + lane * 2);
        unsigned int u2 = *(const unsigned int*)(xb + (size_t)(p2 & 0xFFFF) * 128 + lane * 2);
        unsigned int u3 = *(const unsigned int*)(xb + (size_t)(p3 & 0xFFFF) * 128 + lane * 2);
        float2 e0 = *(const float2*)&semb[(p0 >> 16) * 128 + lane * 2];
        float2 e1 = *(const float2*)&semb[(p1 >> 16) * 128 + lane * 2];
        float2 e2 = *(const float2*)&semb[(p2 >> 16) * 128 + lane * 2];
        float2 e3 = *(const float2*)&semb[(p3 >> 16) * 128 + lane * 2];
        ax += fmaxf(__uint_as_float(u0 << 16) + e0.x, 0.f);
        ay += fmaxf(__uint_as_float(u0 & 0xFFFF0000u) + e0.y, 0.f);
        ax += fmaxf(__uint_as_float(u1 << 16) + e1.x, 0.f);
        ay += fmaxf(__uint_as_float(u1 & 0xFFFF0000u) + e1.y, 0.f);
        ax += fmaxf(__uint_as_float(u2 << 16) + e2.x, 0.f);
        ay += fmaxf(__uint_as_float(u2 & 0xFFFF0000u) + e2.y, 0.f);
        ax += fmaxf(__uint_as_float(u3 << 16) + e3.x, 0.f);
        ay += fmaxf(__uint_as_float(u3 & 0xFFFF0000u) + e3.y, 0.f);
    }
    for (; e < o1; ++e) {
        int pk = csr[e];
        unsigned int u = *(const unsigned int*)(xb + (size_t)(pk & 0xFFFF) * 128 + lane * 2);
        float2 ev = *(const float2*)&semb[(pk >> 16) * 128 + lane * 2];
        ax += fmaxf(__uint_as_float(u << 16) + ev.x, 0.f);
        ay += fmaxf(__uint_as_float(u & 0xFFFF0000u) + ev.y, 0.f);
    }
    unsigned int wv = (unsigned int)f2b(ax) | ((unsigned int)f2b(ay) << 16);
    *(unsigned int*)(aggb + (size_t)node * 128 + lane * 2) = wv;
}

// ---------------- MFMA GEMM1: t[32768,256] = act(A_bf16[32768,128] @ W[128,256] + b) ----------------
// BM=128, BN=64; 256 thr = 4 waves; wave: 32 rows x 64 cols = 2x4 mfma tiles; K=128 fully staged.
// B operand = pre-transposed W1T [256 n][128 k].
__global__ __launch_bounds__(256) void k_gemm1b(const unsigned short* __restrict__ A,
                                                const unsigned short* __restrict__ WT,
                                                const float* __restrict__ bias,
                                                unsigned short* __restrict__ C,
                                                int relu) {
    __shared__ __align__(16) unsigned short As[128][136];   // +16B pad
    __shared__ __align__(16) unsigned short Bs[64][136];
    int tid = threadIdx.x;
    int row0 = blockIdx.y * 128, n0 = blockIdx.x * 64;
    for (int s = tid; s < 2048; s += 256) {                 // A: 128 rows x 16 segs
        int r = s >> 4, c8 = s & 15;
        *(uint4*)&As[r][c8 * 8] = *(const uint4*)(A + (size_t)(row0 + r) * 128 + c8 * 8);
    }
    for (int s = tid; s < 1024; s += 256) {                 // B: 64 rows x 16 segs
        int r = s >> 4, c8 = s & 15;
        *(uint4*)&Bs[r][c8 * 8] = *(const uint4*)(WT + (size_t)(n0 + r) * 128 + c8 * 8);
    }
    __syncthreads();
    int l = tid & 63, w = tid >> 6;
    int fr = l & 15, fk = (l >> 4) * 8;
    f32x4 acc[2][4];
    #pragma unroll
    for (int r = 0; r < 2; r++)
        #pragma unroll
        for (int c = 0; c < 4; c++) acc[r][c] = (f32x4){0.f, 0.f, 0.f, 0.f};
    #pragma unroll 2
    for (int kc = 0; kc < 4; kc++) {
        sh8 a0 = *(const sh8*)&As[w * 32 + fr][kc * 32 + fk];
        sh8 a1 = *(const sh8*)&As[w * 32 + 16 + fr][kc * 32 + fk];
        #pragma unroll
        for (int c = 0; c < 4; c++) {
            sh8 b = *(const sh8*)&Bs[c * 16 + fr][kc * 32 + fk];
            acc[0][c] = __builtin_amdgcn_mfma_f32_16x16x32_bf16(a0, b, acc[0][c], 0, 0, 0);
            acc[1][c] = __builtin_amdgcn_mfma_f32_16x16x32_bf16(a1, b, acc[1][c], 0, 0, 0);
        }
    }
    // D layout: col = l&15, row = (l>>4)*4 + q
    #pragma unroll
    for (int r = 0; r < 2; r++) {
        int rbase = row0 + w * 32 + r * 16 + (l >> 4) * 4;
        #pragma unroll
        for (int c = 0; c < 4; c++) {
            int col = n0 + c * 16 + (l & 15);
            float bv = bias[col];
            #pragma unroll
            for (int q = 0; q < 4; q++) {
                float o = acc[r][c][q] + bv;
                if (relu) o = fmaxf(o, 0.f);
                C[(size_t)(rbase + q) * 256 + col] = f2b(o);
            }
        }
    }
}

// ---------------- MFMA GEMM2 + LN + residual: x += LN(t[32768,256] @ W2[256,128] + b) ----------------
// BM=128, BN=128(full row -> LN in epilogue); 512 thr = 8 waves; wave: 16 rows x 128 cols.
// K=256 staged in 2 chunks of 128. B operand = W2T [128 n][256 k]. Updates fp32 x and bf16 shadow.
__global__ __launch_bounds__(512) void k_gemm2b(const unsigned short* __restrict__ T,
                                                const unsigned short* __restrict__ WT,
                                                const float* __restrict__ bias,
                                                const float* __restrict__ lng,
                                                const float* __restrict__ lnb,
                                                float* __restrict__ x,
                                                unsigned short* __restrict__ xb) {
    __shared__ __align__(16) unsigned short As[128][136];
    __shared__ __align__(16) unsigned short Bs[128][136];
    int tid = threadIdx.x;
    int row0 = blockIdx.x * 128;
    int l = tid & 63, w = tid >> 6;
    int fr = l & 15, fk = (l >> 4) * 8;
    f32x4 acc[8];
    #pragma unroll
    for (int c = 0; c < 8; c++) acc[c] = (f32x4){0.f, 0.f, 0.f, 0.f};
    for (int p = 0; p < 2; p++) {
        if (p) __syncthreads();
        for (int s = tid; s < 2048; s += 512) {             // A chunk: 128 rows x 16 segs
            int r = s >> 4, c8 = s & 15;
            *(uint4*)&As[r][c8 * 8] = *(const uint4*)(T + (size_t)(row0 + r) * 256 + p * 128 + c8 * 8);
        }
        for (int s = tid; s < 2048; s += 512) {             // B chunk: 128 n-rows x 16 segs
            int r = s >> 4, c8 = s & 15;
            *(uint4*)&Bs[r][c8 * 8] = *(const uint4*)(WT + (size_t)r * 256 + p * 128 + c8 * 8);
        }
        __syncthreads();
        #pragma unroll 2
        for (int kc = 0; kc < 4; kc++) {
            sh8 a = *(const sh8*)&As[w * 16 + fr][kc * 32 + fk];
            #pragma unroll
            for (int c = 0; c < 8; c++) {
                sh8 b = *(const sh8*)&Bs[c * 16 + fr][kc * 32 + fk];
                acc[c] = __builtin_amdgcn_mfma_f32_16x16x32_bf16(a, b, acc[c], 0, 0, 0);
            }
        }
    }
    // epilogue: h = acc + bias; LN over 128 cols; x += LN
    float hv[8][4];
    float s0 = 0.f, s1 = 0.f, s2 = 0.f, s3 = 0.f;
    float q0 = 0.f, q1 = 0.f, q2 = 0.f, q3 = 0.f;
    #pragma unroll
    for (int c = 0; c < 8; c++) {
        float bv = bias[c * 16 + (l & 15)];
        #pragma unroll
        for (int q = 0; q < 4; q++) hv[c][q] = acc[c][q] + bv;
        s0 += hv[c][0]; q0 += hv[c][0] * hv[c][0];
        s1 += hv[c][1]; q1 += hv[c][1] * hv[c][1];
        s2 += hv[c][2]; q2 += hv[c][2] * hv[c][2];
        s3 += hv[c][3]; q3 += hv[c][3] * hv[c][3];
    }
    #pragma unroll
    for (int m = 1; m < 16; m <<= 1) {
        s0 += __shfl_xor(s0, m); q0 += __shfl_xor(q0, m);
        s1 += __shfl_xor(s1, m); q1 += __shfl_xor(q1, m);
        s2 += __shfl_xor(s2, m); q2 += __shfl_xor(q2, m);
        s3 += __shfl_xor(s3, m); q3 += __shfl_xor(q3, m);
    }
    float mu[4], rs[4];
    mu[0] = s0 * (1.f / 128.f); rs[0] = rsqrtf(q0 * (1.f / 128.f) - mu[0] * mu[0] + 1e-5f);
    mu[1] = s1 * (1.f / 128.f); rs[1] = rsqrtf(q1 * (1.f / 128.f) - mu[1] * mu[1] + 1e-5f);
    mu[2] = s2 * (1.f / 128.f); rs[2] = rsqrtf(q2 * (1.f / 128.f) - mu[2] * mu[2] + 1e-5f);
    mu[3] = s3 * (1.f / 128.f); rs[3] = rsqrtf(q3 * (1.f / 128.f) - mu[3] * mu[3] + 1e-5f);
    int rbase = row0 + w * 16 + (l >> 4) * 4;
    #pragma unroll
    for (int c = 0; c < 8; c++) {
        int col = c * 16 + (l & 15);
        float g = lng[col], bb = lnb[col];
        #pragma unroll
        for (int q = 0; q < 4; q++) {
            size_t idx = (size_t)(rbase + q) * 128 + col;
            float nx = x[idx] + (hv[c][q] - mu[q]) * rs[q] * g + bb;
            x[idx] = nx;
            xb[idx] = f2b(nx);
        }
    }
}

// ---------------- gate: LN(256) -> relu -> dot(gate_W2), bf16 t input ----------------
__global__ __launch_bounds__(256) void k_gate(const unsigned short* __restrict__ T,
                                              const float* __restrict__ lng,
                                              const float* __restrict__ lnb,
                                              const float* __restrict__ w2,
                                              const float* __restrict__ b2,
                                              float* __restrict__ gate) {
    int row = blockIdx.x * 4 + (threadIdx.x >> 6);
    int lane = threadIdx.x & 63;
    uint2 u = *(const uint2*)(T + (size_t)row * 256 + lane * 4);
    float v0 = __uint_as_float(u.x << 16);
    float v1 = __uint_as_float(u.x & 0xFFFF0000u);
    float v2 = __uint_as_float(u.y << 16);
    float v3 = __uint_as_float(u.y & 0xFFFF0000u);
    float s = v0 + v1 + v2 + v3;
    float q = v0 * v0 + v1 * v1 + v2 * v2 + v3 * v3;
    #pragma unroll
    for (int m = 1; m < 64; m <<= 1) { s += __shfl_xor(s, m); q += __shfl_xor(q, m); }
    float mu = s * (1.f / 256.f);
    float var = q * (1.f / 256.f) - mu * mu;
    float rs = rsqrtf(var + 1e-5f);
    float4 g4 = ((const float4*)lng)[lane];
    float4 e4 = ((const float4*)lnb)[lane];
    float4 w4 = ((const float4*)w2)[lane];
    float a = fmaxf((v0 - mu) * rs * g4.x + e4.x, 0.f) * w4.x
            + fmaxf((v1 - mu) * rs * g4.y + e4.y, 0.f) * w4.y
            + fmaxf((v2 - mu) * rs * g4.z + e4.z, 0.f) * w4.z
            + fmaxf((v3 - mu) * rs * g4.w + e4.w, 0.f) * w4.w;
    #pragma unroll
    for (int m = 1; m < 64; m <<= 1) a += __shfl_xor(a, m);
    if (lane == 0) gate[row] = a + b2[0];
}

// ---------------- attention pooling per graph (fp32 x) ----------------
__global__ __launch_bounds__(256) void k_pool(const float* __restrict__ x,
                                              const float* __restrict__ gate,
                                              float* __restrict__ g) {
    __shared__ float sw[64];
    __shared__ float sacc[128];
    int b = blockIdx.x, tid = threadIdx.x;
    if (tid < 64) {
        float gv = gate[b * 64 + tid];
        float m = gv;
        #pragma unroll
        for (int mk = 1; mk < 64; mk <<= 1) m = fmaxf(m, __shfl_xor(m, mk));
        float e = expf(gv - m);
        float s = e;
        #pragma unroll
        for (int mk = 1; mk < 64; mk <<= 1) s += __shfl_xor(s, mk);
        sw[tid] = e / s;
    }
    __syncthreads();
    int d = tid & 127, h = tid >> 7;
    float acc = 0.f;
    for (int i = h * 32; i < h * 32 + 32; i++)
        acc += sw[i] * x[(size_t)(b * 64 + i) * 128 + d];
    if (h == 0) sacc[d] = acc;
    __syncthreads();
    if (h == 1) g[b * 128 + d] = sacc[d] + acc;
}

// ---------------- residual blocks + head, one block per graph (fp32) ----------------
__global__ __launch_bounds__(128) void k_tail(const float* __restrict__ g_in,
        const float* __restrict__ fc1W, const float* __restrict__ fc1b,
        const float* __restrict__ ln1g, const float* __restrict__ ln1b,
        const float* __restrict__ fc2W, const float* __restrict__ fc2b,
        const float* __restrict__ ln2g, const float* __restrict__ ln2b,
        const float* __restrict__ pW1, const float* __restrict__ pb1,
        const float* __restrict__ pW2, const float* __restrict__ pb2,
        float* __restrict__ out) {
    __shared__ float sg[128], sh[128];
    __shared__ float ps[2], pq[2];
    int b = blockIdx.x, tid = threadIdx.x;
    int w = tid >> 6;
    sg[tid] = g_in[b * 128 + tid];
    __syncthreads();
    for (int r = 0; r < 2; r++) {
        const float* W1 = fc1W + r * 16384;
        float acc = fc1b[r * 128 + tid];
        for (int k = 0; k < 128; k++) acc += sg[k] * W1[k * 128 + tid];
        float s = acc, q = acc * acc;
        #pragma unroll
        for (int m = 1; m < 64; m <<= 1) { s += __shfl_xor(s, m); q += __shfl_xor(q, m); }
        __syncthreads();
        if ((tid & 63) == 0) { ps[w] = s; pq[w] = q; }
        __syncthreads();
        float S = ps[0] + ps[1], Q = pq[0] + pq[1];
        float mu = S * (1.f / 128.f);
        float var = Q * (1.f / 128.f) - mu * mu;
        float z = (acc - mu) * rsqrtf(var + 1e-5f) * ln1g[r * 128 + tid] + ln1b[r * 128 + tid];
        z = gelu_exact(z);
        __syncthreads();
        sh[tid] = z;
        __syncthreads();
        const float* W2 = fc2W + r * 16384;
        float acc2 = fc2b[r * 128 + tid];
        for (int k = 0; k < 128; k++) acc2 += sh[k] * W2[k * 128 + tid];
        s = acc2; q = acc2 * acc2;
        #pragma unroll
        for (int m = 1; m < 64; m <<= 1) { s += __shfl_xor(s, m); q += __shfl_xor(q, m); }
        __syncthreads();
        if ((tid & 63) == 0) { ps[w] = s; pq[w] = q; }
        __syncthreads();
        S = ps[0] + ps[1]; Q = pq[0] + pq[1];
        mu = S * (1.f / 128.f);
        var = Q * (1.f / 128.f) - mu * mu;
        float z2 = (acc2 - mu) * rsqrtf(var + 1e-5f) * ln2g[r * 128 + tid] + ln2b[r * 128 + tid];
        __syncthreads();
        sg[tid] = sg[tid] + z2;
        __syncthreads();
    }
    float acc = pb1[tid];
    for (int k = 0; k < 128; k++) acc += sg[k] * pW1[k * 128 + tid];
    __syncthreads();
    sh[tid] = gelu_exact(acc);
    __syncthreads();
    if (tid < 12) {
        float o = pb2[tid];
        for (int k = 0; k < 128; k++) o += sh[k] * pW2[k * 12 + tid];
        out[b * 12 + tid] = o;
    }
}

// ---------------- launch ----------------
extern "C" void kernel_launch(void* const* d_in, const int* in_sizes, int n_in,
                              void* d_out, int out_size, void* d_ws, size_t ws_size,
                              hipStream_t stream) {
    const float* logits    = (const float*)d_in[0];
    const int*   atom_feat = (const int*)d_in[2];
    const int*   edge_src  = (const int*)d_in[3];
    const int*   edge_dst  = edge_src + N_EDGES;
    const int*   edge_attr = (const int*)d_in[4];
    const float* atom_emb  = (const float*)d_in[6];
    const float* edge_emb  = (const float*)d_in[7];
    const float* gnn_W1    = (const float*)d_in[8];
    const float* gnn_b1    = (const float*)d_in[9];
    const float* gnn_W2    = (const float*)d_in[10];
    const float* gnn_b2    = (const float*)d_in[11];
    const float* gnn_ln_g  = (const float*)d_in[12];
    const float* gnn_ln_b  = (const float*)d_in[13];
    const float* gate_W1   = (const float*)d_in[14];
    const float* gate_b1   = (const float*)d_in[15];
    const float* gate_ln_g = (const float*)d_in[16];
    const float* gate_ln_b = (const float*)d_in[17];
    const float* gate_W2   = (const float*)d_in[18];
    const float* gate_b2   = (const float*)d_in[19];
    const float* res_fc1_W = (const float*)d_in[20];
    const float* res_fc1_b = (const float*)d_in[21];
    const float* res_ln1_g = (const float*)d_in[22];
    const float* res_ln1_b = (const float*)d_in[23];
    const float* res_fc2_W = (const float*)d_in[24];
    const float* res_fc2_b = (const float*)d_in[25];
    const float* res_ln2_g = (const float*)d_in[26];
    const float* res_ln2_b = (const float*)d_in[27];
    const float* pred_W1   = (const float*)d_in[28];
    const float* pred_b1   = (const float*)d_in[29];
    const float* pred_W2   = (const float*)d_in[30];
    const float* pred_b2   = (const float*)d_in[31];
    float* out = (float*)d_out;

    char* w = (char*)d_ws;
    float*          x    = (float*)w;          w += (size_t)N_NODES * 128 * 4;  // 16 MB fp32 master
    unsigned short* xb   = (unsigned short*)w; w += (size_t)N_NODES * 128 * 2;  // 8 MB bf16 shadow
    unsigned short* aggb = (unsigned short*)w; w += (size_t)N_NODES * 128 * 2;  // 8 MB
    unsigned short* t    = (unsigned short*)w; w += (size_t)N_NODES * 256 * 2;  // 16 MB
    unsigned short* W1T  = (unsigned short*)w; w += 3 * 32768 * 2;
    unsigned short* W2T  = (unsigned short*)w; w += 3 * 32768 * 2;
    unsigned short* gW1T = (unsigned short*)w; w += 32768 * 2;
    int*   deg    = (int*)w;   w += N_NODES * 4;
    int*   offs   = (int*)w;   w += (N_NODES + 64) * 4;
    int*   cursor = (int*)w;   w += N_NODES * 4;
    int*   csr    = (int*)w;   w += N_EDGES * 4;
    float* gate   = (float*)w; w += N_NODES * 4;
    float* gpool  = (float*)w; w += B_GRAPHS * 128 * 4;

    // weight prep + CSR build (independent)
    k_prep<<<7 * 32768 / 256, 256, 0, stream>>>(gnn_W1, gnn_W2, gate_W1, W1T, W2T, gW1T);
    k_zero<<<N_NODES / 256, 256, 0, stream>>>(deg, N_NODES);
    k_deg<<<N_EDGES / 256, 256, 0, stream>>>(edge_dst, deg);
    k_scan<<<1, 1024, 0, stream>>>(deg, offs, cursor);
    k_scatter<<<N_EDGES / 256, 256, 0, stream>>>(edge_src, edge_dst, edge_attr, cursor, csr);

    // x = logits[mask] + atom_emb[feat]
    k_build_x<<<N_NODES * 32 / 256, 256, 0, stream>>>(logits, atom_feat, atom_emb, x, xb);

    // 3 GNN layers
    for (int l = 0; l < 3; l++) {
        k_agg<<<N_NODES / 4, 256, 0, stream>>>(xb, offs, csr, edge_emb, aggb);
        k_gemm1b<<<dim3(4, N_NODES / 128), 256, 0, stream>>>(
            aggb, W1T + l * 32768, gnn_b1 + l * 256, t, 1);
        k_gemm2b<<<N_NODES / 128, 512, 0, stream>>>(
            t, W2T + l * 32768, gnn_b2 + l * 128,
            gnn_ln_g + l * 128, gnn_ln_b + l * 128, x, xb);
    }

    // gate logits: t = x @ gate_W1 + b (no relu), then LN->relu->dot
    k_gemm1b<<<dim3(4, N_NODES / 128), 256, 0, stream>>>(xb, gW1T, gate_b1, t, 0);
    k_gate<<<N_NODES / 4, 256, 0, stream>>>(t, gate_ln_g, gate_ln_b, gate_W2, gate_b2, gate);

    // attention pooling
    k_pool<<<B_GRAPHS, 256, 0, stream>>>(x, gate, gpool);

    // residual blocks + head
    k_tail<<<B_GRAPHS, 128, 0, stream>>>(gpool,
        res_fc1_W, res_fc1_b, res_ln1_g, res_ln1_b,
        res_fc2_W, res_fc2_b, res_ln2_g, res_ln2_b,
        pred_W1, pred_b1, pred_W2, pred_b2, out);
}